// Round 5
// baseline (216.552 us; speedup 1.0000x reference)
//
#include <hip/hip_runtime.h>
#include <math.h>

// B=8, T=2048, C=1024, H=64. bf16 MFMA proj + flash attention (no-max softmax).
namespace {
constexpr int BATCH = 8;
constexpr int TSEQ  = 2048;
constexpr int CDIM  = 1024;
constexpr int HDIM  = 64;
constexpr int MROWS = BATCH * TSEQ;         // 16384
// fold softmax scale (1/8) AND log2(e) into Wq so softmax can use exp2
constexpr float QSCALE = 0.125f * 1.4426950408889634f;
}

typedef __attribute__((ext_vector_type(4))) float  f32x4;
typedef __attribute__((ext_vector_type(8))) short  s16x8;   // 8 bf16 (4 VGPRs)
typedef __attribute__((ext_vector_type(4))) unsigned short u16x4;

__device__ __forceinline__ unsigned short f2bf(float f) {
    union { float f; unsigned u; } c{f};
    unsigned r = c.u + 0x7FFFu + ((c.u >> 16) & 1u);   // RNE
    return (unsigned short)(r >> 16);
}

__device__ __forceinline__ s16x8 pack_bf16x8(const float v[8]) {
    union { s16x8 s; unsigned u[4]; } w;
    #pragma unroll
    for (int i = 0; i < 4; ++i)
        w.u[i] = (unsigned)f2bf(v[2 * i]) | ((unsigned)f2bf(v[2 * i + 1]) << 16);
    return w.s;
}

// ---------------------------------------------------------------------------
// Pre-swizzle W = [Wq*QSCALE | Wk | Wv] into bf16 B-fragment order:
// swz[((ksg*12 + tn)*64 + lane)*8 + j] = W'[k=ksg*32+(lane>>4)*8+j][n=tn*16+(lane&15)]
// ---------------------------------------------------------------------------
__global__ __launch_bounds__(256)
void wswz_kernel(const float* __restrict__ Wk, const float* __restrict__ Wq,
                 const float* __restrict__ Wv, unsigned short* __restrict__ swz)
{
    const int idx  = blockIdx.x * 256 + threadIdx.x;   // 0 .. 196607
    const int j    = idx & 7;
    const int lane = (idx >> 3) & 63;
    const int rest = idx >> 9;          // ksg*12 + tn
    const int tn   = rest % 12;
    const int ksg  = rest / 12;
    const int kk   = ksg * 32 + (lane >> 4) * 8 + j;
    const int n    = tn * 16 + (lane & 15);
    float val;
    if (n < 64)       val = Wq[kk * HDIM + n] * QSCALE;
    else if (n < 128) val = Wk[kk * HDIM + (n - 64)];
    else              val = Wv[kk * HDIM + (n - 128)];
    swz[idx] = f2bf(val);
}

// ---------------------------------------------------------------------------
// Fused projection. Block = 16 rows x 192 cols, 8 waves (512 thr):
//   wave w: cq = w&3 (48-col quarter), kh = w>>2 (K-half of 512).
// 1024 blocks x 8 waves = 8192 waves -> 8 waves/SIMD. LDS combine of kh pairs.
// Outputs q,k row-major bf16 [16384][64]; v transposed vt[b][64][2048].
// ---------------------------------------------------------------------------
__global__ __launch_bounds__(512, 8)
void proj_kernel(const float* __restrict__ x, const unsigned short* __restrict__ swz,
                 unsigned short* __restrict__ q, unsigned short* __restrict__ k,
                 unsigned short* __restrict__ vt)
{
    __shared__ float Cl[8][16][52];   // 26.6 KB; stride 52 breaks pow2 aliasing

    const int tid  = threadIdx.x;
    const int lane = tid & 63, wave = tid >> 6;
    const int quad = lane >> 4, l15 = lane & 15;
    const int cq   = wave & 3;
    const int kh   = wave >> 2;
    const int m0   = blockIdx.x * 16;

    f32x4 acc[3] = {};
    const float* xp = x + (size_t)(m0 + l15) * CDIM + kh * 512 + quad * 8;
    const unsigned short* bp = swz + ((size_t)((kh * 16) * 12 + cq * 3) * 64 + lane) * 8;

    // 2-stage pipeline on the HBM-streaming x loads
    float4 xa = *(const float4*)(xp);
    float4 xb = *(const float4*)(xp + 4);

    #pragma unroll
    for (int ks = 0; ks < 16; ++ks) {
        float4 nxa, nxb;
        if (ks < 15) {
            nxa = *(const float4*)(xp + 32);
            nxb = *(const float4*)(xp + 36);
            xp += 32;
        }
        s16x8 b0 = *(const s16x8*)(bp);
        s16x8 b1 = *(const s16x8*)(bp + 512);
        s16x8 b2 = *(const s16x8*)(bp + 1024);
        bp += 6144;
        const float av[8] = {xa.x, xa.y, xa.z, xa.w, xb.x, xb.y, xb.z, xb.w};
        const s16x8 af = pack_bf16x8(av);
        acc[0] = __builtin_amdgcn_mfma_f32_16x16x32_bf16(af, b0, acc[0], 0, 0, 0);
        acc[1] = __builtin_amdgcn_mfma_f32_16x16x32_bf16(af, b1, acc[1], 0, 0, 0);
        acc[2] = __builtin_amdgcn_mfma_f32_16x16x32_bf16(af, b2, acc[2], 0, 0, 0);
        if (ks < 15) { xa = nxa; xb = nxb; }
    }

    // partials -> LDS (C/D layout: row = quad*4+r, col-in-slice = t*16+l15)
    #pragma unroll
    for (int t = 0; t < 3; ++t)
        #pragma unroll
        for (int r = 0; r < 4; ++r)
            Cl[wave][quad * 4 + r][t * 16 + l15] = acc[t][r];
    __syncthreads();

    // combine kh pairs + store. Fused col n: q=0..63, k=64..127, v=128..191.
    // slice = n/48 (cq), idx = n%48; partials at Cl[cq] (kh0) + Cl[4+cq] (kh1).
    if (tid < 256) {           // q rows
        const int r  = tid >> 4;
        const int c4 = (tid & 15) << 2;
        u16x4 pq;
        #pragma unroll
        for (int j = 0; j < 4; ++j) {
            const int n = c4 + j, sl = n / 48, ix = n % 48;
            pq[j] = f2bf(Cl[sl][r][ix] + Cl[4 + sl][r][ix]);
        }
        *(u16x4*)(q + (size_t)(m0 + r) * HDIM + c4) = pq;
    } else {                   // k rows
        const int t2 = tid - 256;
        const int r  = t2 >> 4;
        const int c4 = (t2 & 15) << 2;
        u16x4 pk;
        #pragma unroll
        for (int j = 0; j < 4; ++j) {
            const int n = 64 + c4 + j, sl = n / 48, ix = n % 48;
            pk[j] = f2bf(Cl[sl][r][ix] + Cl[4 + sl][r][ix]);
        }
        *(u16x4*)(k + (size_t)(m0 + r) * HDIM + c4) = pk;
    }
    if (tid < 256) {           // v transposed: u16x4 along t
        const int h  = tid & 63;
        const int rg = tid >> 6;
        const int n = 128 + h, sl = n / 48, ix = n % 48;
        u16x4 pv;
        #pragma unroll
        for (int j = 0; j < 4; ++j)
            pv[j] = f2bf(Cl[sl][rg * 4 + j][ix] + Cl[4 + sl][rg * 4 + j][ix]);
        const int rowg = m0 + rg * 4;
        const int bb = rowg >> 11, tl = rowg & 2047;
        *(u16x4*)(vt + ((size_t)bb * HDIM + h) * TSEQ + tl) = pv;
    }
}

// ---------------------------------------------------------------------------
// Flash attention, no-max softmax. Block = one 16-row q-tile, 8 waves (512
// thr) splitting the KV chunks (BN=64) round-robin; partial (O,l) combine in
// LDS. In-loop P-transform buffer aliased with epilogue O buffer (union) to
// keep LDS at 35 KB -> 4 blocks/CU -> 8 waves/SIMD. Big tiles first.
// ---------------------------------------------------------------------------
__global__ __launch_bounds__(512, 8)
void attn_kernel(const unsigned short* __restrict__ q, const unsigned short* __restrict__ k,
                 const unsigned short* __restrict__ vt, float* __restrict__ out)
{
    __shared__ __align__(16) char smem[8 * 16 * 68 * 4];   // 34816 B, aliased
    __shared__ float llds[8][16];
    typedef unsigned short PlT[16][72];   // per-wave P transform (in loop)
    typedef float          OlT[16][68];   // per-wave O partials (epilogue)
    PlT* Pl = (PlT*)smem;
    OlT* Ol = (OlT*)smem;

    const int tid  = threadIdx.x;
    const int lane = tid & 63, wave = tid >> 6;
    const int quad = lane >> 4, l15 = lane & 15;
    const int b    = blockIdx.y;
    const int ti   = 127 - (int)blockIdx.x;    // biggest tiles first
    const int m0   = ti * 16;

    const unsigned short* qb  = q  + (size_t)b * TSEQ * HDIM;
    const unsigned short* kb  = k  + (size_t)b * TSEQ * HDIM;
    const unsigned short* vtb = vt + (size_t)b * HDIM * TSEQ;

    // Q A-fragments (A[m=l15][k=quad*8+j]), held for the whole pass
    s16x8 aq[2];
    #pragma unroll
    for (int ks = 0; ks < 2; ++ks)
        aq[ks] = *(const s16x8*)(qb + (size_t)(m0 + l15) * HDIM + ks * 32 + quad * 8);

    f32x4 O[4] = {};
    float l_lane[4] = {0.f, 0.f, 0.f, 0.f};

    const int nt = ti / 4 + 1;                 // # of 64-wide KV chunks
    for (int it = wave; it < nt; it += 8) {
        const int n0 = it * 64;

        // S = Q K^T (K fragments transient: loaded inside the subtile loop)
        f32x4 S[4] = {};
        #pragma unroll
        for (int st = 0; st < 4; ++st) {
            const unsigned short* kr = kb + (size_t)(n0 + st * 16 + l15) * HDIM + quad * 8;
            const s16x8 k0 = *(const s16x8*)(kr);
            const s16x8 k1 = *(const s16x8*)(kr + 32);
            S[st] = __builtin_amdgcn_mfma_f32_16x16x32_bf16(aq[0], k0, S[st], 0, 0, 0);
            S[st] = __builtin_amdgcn_mfma_f32_16x16x32_bf16(aq[1], k1, S[st], 0, 0, 0);
        }

        // causal mask + exp2 (no max subtraction; scores bounded)
        const int rowbase = m0 + quad * 4;
        #pragma unroll
        for (int st = 0; st < 4; ++st) {
            const int col = n0 + st * 16 + l15;
            #pragma unroll
            for (int r = 0; r < 4; ++r) {
                const float p = (col > rowbase + r) ? 0.f : exp2f(S[st][r]);
                S[st][r] = p;
                l_lane[r] += p;
            }
        }

        // P: C-layout -> A-layout via per-wave LDS slice (no barrier needed)
        #pragma unroll
        for (int st = 0; st < 4; ++st)
            #pragma unroll
            for (int r = 0; r < 4; ++r)
                Pl[wave][quad * 4 + r][st * 16 + l15] = f2bf(S[st][r]);
        s16x8 pa[2];
        #pragma unroll
        for (int ks = 0; ks < 2; ++ks)
            pa[ks] = *(const s16x8*)&Pl[wave][l15][ks * 32 + quad * 8];

        // O += P V  (V fragments loaded per-hst to cap register pressure)
        #pragma unroll
        for (int hst = 0; hst < 4; ++hst) {
            const unsigned short* vr = vtb + (size_t)(hst * 16 + l15) * TSEQ + n0 + quad * 8;
            const s16x8 v0 = *(const s16x8*)(vr);
            const s16x8 v1 = *(const s16x8*)(vr + 32);
            O[hst] = __builtin_amdgcn_mfma_f32_16x16x32_bf16(pa[0], v0, O[hst], 0, 0, 0);
            O[hst] = __builtin_amdgcn_mfma_f32_16x16x32_bf16(pa[1], v1, O[hst], 0, 0, 0);
        }
    }

    // one-time l reduction across the 16 lanes of each row group
    #pragma unroll
    for (int off = 1; off < 16; off <<= 1)
        #pragma unroll
        for (int r = 0; r < 4; ++r)
            l_lane[r] += __shfl_xor(l_lane[r], off);

    __syncthreads();   // ALL waves done with their Pl slices before Ol overwrite

    #pragma unroll
    for (int hst = 0; hst < 4; ++hst)
        #pragma unroll
        for (int r = 0; r < 4; ++r)
            Ol[wave][quad * 4 + r][hst * 16 + l15] = O[hst][r];
    if (l15 == 0) {
        #pragma unroll
        for (int r = 0; r < 4; ++r)
            llds[wave][quad * 4 + r] = l_lane[r];
    }
    __syncthreads();

    // combine 8 waves + normalize + store (first 256 threads)
    if (tid < 256) {
        const int r  = tid >> 4;
        const int c4 = (tid & 15) << 2;
        float lv = 0.f;
        #pragma unroll
        for (int w = 0; w < 8; ++w) lv += llds[w][r];
        const float inv = 1.f / lv;
        float4 t;
        float* tp = &t.x;
        #pragma unroll
        for (int j = 0; j < 4; ++j) {
            float s = 0.f;
            #pragma unroll
            for (int w = 0; w < 8; ++w) s += Ol[w][r][c4 + j];
            tp[j] = s * inv;
        }
        *(float4*)(out + (size_t)b * TSEQ * HDIM + (size_t)(m0 + r) * HDIM + c4) = t;
    }
}

// ---------------------------------------------------------------------------
extern "C" void kernel_launch(void* const* d_in, const int* in_sizes, int n_in,
                              void* d_out, int out_size, void* d_ws, size_t ws_size,
                              hipStream_t stream) {
    const float* x  = (const float*)d_in[0];
    const float* Wk = (const float*)d_in[1];
    const float* Wq = (const float*)d_in[2];
    const float* Wv = (const float*)d_in[3];
    float* out = (float*)d_out;

    unsigned short* swz = (unsigned short*)d_ws;            // 196608 elems
    unsigned short* qw  = swz + 196608;
    unsigned short* kw  = qw + (size_t)MROWS * HDIM;
    unsigned short* vtw = kw + (size_t)MROWS * HDIM;

    wswz_kernel<<<dim3(768), 256, 0, stream>>>(Wk, Wq, Wv, swz);
    proj_kernel<<<dim3(MROWS / 16), 512, 0, stream>>>(x, swz, qw, kw, vtw);
    attn_kernel<<<dim3(128, BATCH), 512, 0, stream>>>(qw, kw, vtw, out);
}

// Round 6
// 181.908 us; speedup vs baseline: 1.1904x; 1.1904x over previous
//
#include <hip/hip_runtime.h>
#include <math.h>

// B=8, T=2048, C=1024, H=64. bf16 MFMA proj + split-KV flash attention.
namespace {
constexpr int BATCH = 8;
constexpr int TSEQ  = 2048;
constexpr int CDIM  = 1024;
constexpr int HDIM  = 64;
constexpr int MROWS = BATCH * TSEQ;         // 16384
constexpr int NTILE = 128;                  // 16-row q-tiles per batch
constexpr int NSLC  = 4;                    // KV slices per q-tile
// fold softmax scale (1/8) AND log2(e) into Wq so softmax can use exp2
constexpr float QSCALE = 0.125f * 1.4426950408889634f;
}

typedef __attribute__((ext_vector_type(4))) float  f32x4;
typedef __attribute__((ext_vector_type(8))) short  s16x8;   // 8 bf16 (4 VGPRs)
typedef __attribute__((ext_vector_type(4))) unsigned short u16x4;

__device__ __forceinline__ unsigned short f2bf(float f) {
    union { float f; unsigned u; } c{f};
    unsigned r = c.u + 0x7FFFu + ((c.u >> 16) & 1u);   // RNE
    return (unsigned short)(r >> 16);
}

__device__ __forceinline__ s16x8 pack_bf16x8(const float v[8]) {
    union { s16x8 s; unsigned u[4]; } w;
    #pragma unroll
    for (int i = 0; i < 4; ++i)
        w.u[i] = (unsigned)f2bf(v[2 * i]) | ((unsigned)f2bf(v[2 * i + 1]) << 16);
    return w.s;
}

// ---------------------------------------------------------------------------
// Pre-swizzle W = [Wq*QSCALE | Wk | Wv] into bf16 B-fragment order:
// swz[((ksg*12 + tn)*64 + lane)*8 + j] = W'[k=ksg*32+(lane>>4)*8+j][n=tn*16+(lane&15)]
// ---------------------------------------------------------------------------
__global__ __launch_bounds__(256)
void wswz_kernel(const float* __restrict__ Wk, const float* __restrict__ Wq,
                 const float* __restrict__ Wv, unsigned short* __restrict__ swz)
{
    const int idx  = blockIdx.x * 256 + threadIdx.x;   // 0 .. 196607
    const int j    = idx & 7;
    const int lane = (idx >> 3) & 63;
    const int rest = idx >> 9;          // ksg*12 + tn
    const int tn   = rest % 12;
    const int ksg  = rest / 12;
    const int kk   = ksg * 32 + (lane >> 4) * 8 + j;
    const int n    = tn * 16 + (lane & 15);
    float val;
    if (n < 64)       val = Wq[kk * HDIM + n] * QSCALE;
    else if (n < 128) val = Wk[kk * HDIM + (n - 64)];
    else              val = Wv[kk * HDIM + (n - 128)];
    swz[idx] = f2bf(val);
}

// ---------------------------------------------------------------------------
// Fused projection. Block = 16 rows x 192 cols, 8 waves (512 thr):
//   wave w: cq = w&3 (48-col quarter), kh = w>>2 (K-half of 512).
// launch_bounds(512,4): VGPR cap 128 -> no spill. LDS combine of kh pairs.
// Outputs q,k row-major bf16 [16384][64]; v transposed vt[b][64][2048].
// ---------------------------------------------------------------------------
__global__ __launch_bounds__(512, 4)
void proj_kernel(const float* __restrict__ x, const unsigned short* __restrict__ swz,
                 unsigned short* __restrict__ q, unsigned short* __restrict__ k,
                 unsigned short* __restrict__ vt)
{
    __shared__ float Cl[8][16][52];   // 26.6 KB; stride 52 breaks pow2 aliasing

    const int tid  = threadIdx.x;
    const int lane = tid & 63, wave = tid >> 6;
    const int quad = lane >> 4, l15 = lane & 15;
    const int cq   = wave & 3;
    const int kh   = wave >> 2;
    const int m0   = blockIdx.x * 16;

    f32x4 acc[3] = {};
    const float* xp = x + (size_t)(m0 + l15) * CDIM + kh * 512 + quad * 8;
    const unsigned short* bp = swz + ((size_t)((kh * 16) * 12 + cq * 3) * 64 + lane) * 8;

    // 2-stage pipeline on the HBM-streaming x loads
    float4 xa = *(const float4*)(xp);
    float4 xb = *(const float4*)(xp + 4);

    #pragma unroll
    for (int ks = 0; ks < 16; ++ks) {
        float4 nxa, nxb;
        if (ks < 15) {
            nxa = *(const float4*)(xp + 32);
            nxb = *(const float4*)(xp + 36);
            xp += 32;
        }
        s16x8 b0 = *(const s16x8*)(bp);
        s16x8 b1 = *(const s16x8*)(bp + 512);
        s16x8 b2 = *(const s16x8*)(bp + 1024);
        bp += 6144;
        const float av[8] = {xa.x, xa.y, xa.z, xa.w, xb.x, xb.y, xb.z, xb.w};
        const s16x8 af = pack_bf16x8(av);
        acc[0] = __builtin_amdgcn_mfma_f32_16x16x32_bf16(af, b0, acc[0], 0, 0, 0);
        acc[1] = __builtin_amdgcn_mfma_f32_16x16x32_bf16(af, b1, acc[1], 0, 0, 0);
        acc[2] = __builtin_amdgcn_mfma_f32_16x16x32_bf16(af, b2, acc[2], 0, 0, 0);
        if (ks < 15) { xa = nxa; xb = nxb; }
    }

    // partials -> LDS (C/D layout: row = quad*4+r, col-in-slice = t*16+l15)
    #pragma unroll
    for (int t = 0; t < 3; ++t)
        #pragma unroll
        for (int r = 0; r < 4; ++r)
            Cl[wave][quad * 4 + r][t * 16 + l15] = acc[t][r];
    __syncthreads();

    // combine kh pairs + store. Fused col n: q=0..63, k=64..127, v=128..191.
    if (tid < 256) {           // q rows
        const int r  = tid >> 4;
        const int c4 = (tid & 15) << 2;
        u16x4 pq;
        #pragma unroll
        for (int j = 0; j < 4; ++j) {
            const int n = c4 + j, sl = n / 48, ix = n % 48;
            pq[j] = f2bf(Cl[sl][r][ix] + Cl[4 + sl][r][ix]);
        }
        *(u16x4*)(q + (size_t)(m0 + r) * HDIM + c4) = pq;
    } else {                   // k rows
        const int t2 = tid - 256;
        const int r  = t2 >> 4;
        const int c4 = (t2 & 15) << 2;
        u16x4 pk;
        #pragma unroll
        for (int j = 0; j < 4; ++j) {
            const int n = 64 + c4 + j, sl = n / 48, ix = n % 48;
            pk[j] = f2bf(Cl[sl][r][ix] + Cl[4 + sl][r][ix]);
        }
        *(u16x4*)(k + (size_t)(m0 + r) * HDIM + c4) = pk;
    }
    if (tid < 256) {           // v transposed: u16x4 along t
        const int h  = tid & 63;
        const int rg = tid >> 6;
        const int n = 128 + h, sl = n / 48, ix = n % 48;
        u16x4 pv;
        #pragma unroll
        for (int j = 0; j < 4; ++j)
            pv[j] = f2bf(Cl[sl][rg * 4 + j][ix] + Cl[4 + sl][rg * 4 + j][ix]);
        const int rowg = m0 + rg * 4;
        const int bb = rowg >> 11, tl = rowg & 2047;
        *(u16x4*)(vt + ((size_t)bb * HDIM + h) * TSEQ + tl) = pv;
    }
}

// ---------------------------------------------------------------------------
// Flash attention pass 1 (split-KV). Block = (q-tile ti, slice s, batch b),
// 256 thr / 4 waves. Slice s owns chunks c ≡ s (mod 4), c < nt = ti/4+1;
// waves round-robin within the slice (each wave <= 2 chunks). Partial
// (O[16][64], l[16]) written to workspace; combined by attn_combine.
// 4096 blocks (4x oversubscribed), big tiles dispatched first.
// ---------------------------------------------------------------------------
__global__ __launch_bounds__(256, 4)
void attn_part(const unsigned short* __restrict__ q, const unsigned short* __restrict__ k,
               const unsigned short* __restrict__ vt, float* __restrict__ Opart,
               float* __restrict__ lpart)
{
    __shared__ unsigned short Pl[4][16][72];   // per-wave P transform
    __shared__ float Olds[4][16][68];          // per-wave O partials
    __shared__ float llds[4][16];

    const int tid  = threadIdx.x;
    const int lane = tid & 63, wave = tid >> 6;
    const int quad = lane >> 4, l15 = lane & 15;
    const int b    = blockIdx.y;
    const int s    = blockIdx.x & 3;
    const int ti   = 127 - ((int)blockIdx.x >> 2);   // biggest tiles first
    const int m0   = ti * 16;
    const int nt   = ti / 4 + 1;

    const unsigned short* qb  = q  + (size_t)b * TSEQ * HDIM;
    const unsigned short* kb  = k  + (size_t)b * TSEQ * HDIM;
    const unsigned short* vtb = vt + (size_t)b * HDIM * TSEQ;

    // Q A-fragments (A[m=l15][k=quad*8+j])
    s16x8 aq[2];
    #pragma unroll
    for (int ks = 0; ks < 2; ++ks)
        aq[ks] = *(const s16x8*)(qb + (size_t)(m0 + l15) * HDIM + ks * 32 + quad * 8);

    f32x4 O[4] = {};
    float l_lane[4] = {0.f, 0.f, 0.f, 0.f};

    // chunks of this slice: c = s + 4*m; wave handles m = wave, wave+4, ...
    for (int c = s + 4 * wave; c < nt; c += 16) {
        const int n0 = c * 64;

        // S = Q K^T
        f32x4 S[4] = {};
        #pragma unroll
        for (int st = 0; st < 4; ++st) {
            const unsigned short* kr = kb + (size_t)(n0 + st * 16 + l15) * HDIM + quad * 8;
            const s16x8 k0 = *(const s16x8*)(kr);
            const s16x8 k1 = *(const s16x8*)(kr + 32);
            S[st] = __builtin_amdgcn_mfma_f32_16x16x32_bf16(aq[0], k0, S[st], 0, 0, 0);
            S[st] = __builtin_amdgcn_mfma_f32_16x16x32_bf16(aq[1], k1, S[st], 0, 0, 0);
        }

        // causal mask + exp2 (no max subtraction; scores bounded ~|3|)
        const int rowbase = m0 + quad * 4;
        #pragma unroll
        for (int st = 0; st < 4; ++st) {
            const int col = n0 + st * 16 + l15;
            #pragma unroll
            for (int r = 0; r < 4; ++r) {
                const float p = (col > rowbase + r) ? 0.f : exp2f(S[st][r]);
                S[st][r] = p;
                l_lane[r] += p;
            }
        }

        // P: C-layout -> A-layout via per-wave LDS slice (same wave, no barrier)
        #pragma unroll
        for (int st = 0; st < 4; ++st)
            #pragma unroll
            for (int r = 0; r < 4; ++r)
                Pl[wave][quad * 4 + r][st * 16 + l15] = f2bf(S[st][r]);
        s16x8 pa[2];
        #pragma unroll
        for (int ks = 0; ks < 2; ++ks)
            pa[ks] = *(const s16x8*)&Pl[wave][l15][ks * 32 + quad * 8];

        // O += P V
        #pragma unroll
        for (int hst = 0; hst < 4; ++hst) {
            const unsigned short* vr = vtb + (size_t)(hst * 16 + l15) * TSEQ + n0 + quad * 8;
            const s16x8 v0 = *(const s16x8*)(vr);
            const s16x8 v1 = *(const s16x8*)(vr + 32);
            O[hst] = __builtin_amdgcn_mfma_f32_16x16x32_bf16(pa[0], v0, O[hst], 0, 0, 0);
            O[hst] = __builtin_amdgcn_mfma_f32_16x16x32_bf16(pa[1], v1, O[hst], 0, 0, 0);
        }
    }

    // l reduction across the 16 lanes of each row group
    #pragma unroll
    for (int off = 1; off < 16; off <<= 1)
        #pragma unroll
        for (int r = 0; r < 4; ++r)
            l_lane[r] += __shfl_xor(l_lane[r], off);

    #pragma unroll
    for (int hst = 0; hst < 4; ++hst)
        #pragma unroll
        for (int r = 0; r < 4; ++r)
            Olds[wave][quad * 4 + r][hst * 16 + l15] = O[hst][r];
    if (l15 == 0) {
        #pragma unroll
        for (int r = 0; r < 4; ++r)
            llds[wave][quad * 4 + r] = l_lane[r];
    }
    __syncthreads();

    // combine 4 waves -> block partial, store to workspace
    const size_t p = ((size_t)b * NTILE + ti) * NSLC + s;
    {
        const int r  = tid >> 4;
        const int c4 = (tid & 15) << 2;
        float4 t;
        float* tp = &t.x;
        #pragma unroll
        for (int j = 0; j < 4; ++j)
            tp[j] = Olds[0][r][c4 + j] + Olds[1][r][c4 + j] +
                    Olds[2][r][c4 + j] + Olds[3][r][c4 + j];
        *(float4*)(Opart + (p * 16 + r) * HDIM + c4) = t;
        if ((tid & 15) == 0)
            lpart[p * 16 + r] = llds[0][r] + llds[1][r] + llds[2][r] + llds[3][r];
    }
}

// ---------------------------------------------------------------------------
// Pass 2: out[row][c4..] = sum_s Opart / sum_s lpart.
// ---------------------------------------------------------------------------
__global__ __launch_bounds__(256)
void attn_combine(const float* __restrict__ Opart, const float* __restrict__ lpart,
                  float* __restrict__ out)
{
    const int g   = blockIdx.x * 256 + threadIdx.x;   // 0 .. 262143
    const int row = g >> 4;                           // 0 .. 16383
    const int c4  = (g & 15) << 2;
    const int b   = row >> 11, t = row & 2047;
    const int ti  = t >> 4,  r = t & 15;
    const size_t p0 = ((size_t)b * NTILE + ti) * NSLC;

    float4 acc = {0.f, 0.f, 0.f, 0.f};
    float lv = 0.f;
    #pragma unroll
    for (int s = 0; s < NSLC; ++s) {
        const float4 t4 = *(const float4*)(Opart + ((p0 + s) * 16 + r) * HDIM + c4);
        acc.x += t4.x; acc.y += t4.y; acc.z += t4.z; acc.w += t4.w;
        lv += lpart[(p0 + s) * 16 + r];
    }
    const float inv = 1.f / lv;
    float4 o = {acc.x * inv, acc.y * inv, acc.z * inv, acc.w * inv};
    *(float4*)(out + (size_t)row * HDIM + c4) = o;
}

// ---------------------------------------------------------------------------
extern "C" void kernel_launch(void* const* d_in, const int* in_sizes, int n_in,
                              void* d_out, int out_size, void* d_ws, size_t ws_size,
                              hipStream_t stream) {
    const float* x  = (const float*)d_in[0];
    const float* Wk = (const float*)d_in[1];
    const float* Wq = (const float*)d_in[2];
    const float* Wv = (const float*)d_in[3];
    float* out = (float*)d_out;

    // ws layout: swz | q | k | vt (bf16) then Opart | lpart (fp32). ~24 MB.
    unsigned short* swz = (unsigned short*)d_ws;            // 196608 elems
    unsigned short* qw  = swz + 196608;
    unsigned short* kw  = qw + (size_t)MROWS * HDIM;
    unsigned short* vtw = kw + (size_t)MROWS * HDIM;
    float* Opart = (float*)(vtw + (size_t)MROWS * HDIM);    // 4096*16*64 fp32
    float* lpart = Opart + (size_t)BATCH * NTILE * NSLC * 16 * HDIM;

    wswz_kernel<<<dim3(768), 256, 0, stream>>>(Wk, Wq, Wv, swz);
    proj_kernel<<<dim3(MROWS / 16), 512, 0, stream>>>(x, swz, qw, kw, vtw);
    attn_part<<<dim3(NTILE * NSLC, BATCH), 256, 0, stream>>>(qw, kw, vtw, Opart, lpart);
    attn_combine<<<dim3(MROWS * 16 / 256), 256, 0, stream>>>(Opart, lpart, out);
}

// Round 7
// 157.741 us; speedup vs baseline: 1.3728x; 1.1532x over previous
//
#include <hip/hip_runtime.h>
#include <math.h>

// B=8, T=2048, C=1024, H=64. bf16 MFMA proj + split-KV flash attention.
namespace {
constexpr int BATCH = 8;
constexpr int TSEQ  = 2048;
constexpr int CDIM  = 1024;
constexpr int HDIM  = 64;
constexpr int MROWS = BATCH * TSEQ;         // 16384
constexpr int NTILE = 128;                  // 16-row q-tiles per batch
constexpr int NSLC  = 4;                    // KV slices per q-tile
// fold softmax scale (1/8) AND log2(e) into Wq so softmax can use exp2
constexpr float QSCALE = 0.125f * 1.4426950408889634f;
}

typedef __attribute__((ext_vector_type(4))) float  f32x4;
typedef __attribute__((ext_vector_type(8))) short  s16x8;   // 8 bf16 (4 VGPRs)
typedef __attribute__((ext_vector_type(4))) unsigned short u16x4;

__device__ __forceinline__ unsigned short f2bf(float f) {
    union { float f; unsigned u; } c{f};
    unsigned r = c.u + 0x7FFFu + ((c.u >> 16) & 1u);   // RNE
    return (unsigned short)(r >> 16);
}

// ---------------------------------------------------------------------------
// Pre-swizzle W = [Wq*QSCALE | Wk | Wv] into bf16 B-fragment order:
// swz[((ksg*12 + tn)*64 + lane)*8 + j] = W'[k=ksg*32+(lane>>4)*8+j][n=tn*16+(lane&15)]
// ---------------------------------------------------------------------------
__global__ __launch_bounds__(256)
void wswz_kernel(const float* __restrict__ Wk, const float* __restrict__ Wq,
                 const float* __restrict__ Wv, unsigned short* __restrict__ swz)
{
    const int idx  = blockIdx.x * 256 + threadIdx.x;   // 0 .. 196607
    const int j    = idx & 7;
    const int lane = (idx >> 3) & 63;
    const int rest = idx >> 9;          // ksg*12 + tn
    const int tn   = rest % 12;
    const int ksg  = rest / 12;
    const int kk   = ksg * 32 + (lane >> 4) * 8 + j;
    const int n    = tn * 16 + (lane & 15);
    float val;
    if (n < 64)       val = Wq[kk * HDIM + n] * QSCALE;
    else if (n < 128) val = Wk[kk * HDIM + (n - 64)];
    else              val = Wv[kk * HDIM + (n - 128)];
    swz[idx] = f2bf(val);
}

// ---------------------------------------------------------------------------
// Fused projection v3: stage-once / compute-many.
// 512 blocks x 512 thr. Block owns 32 rows x full K=1024.
// Phase 1: stream 32x1024 fp32 x -> bf16 -> LDS (16 independent float4
//          loads per thread, all outstanding: one HBM latency exposure).
// Phase 2: wave (mh, cq) computes rows mh*16..+16, cols cq*48..+48 over
//          full K: 96 MFMAs from ds_read_b128 A-frags + prefetched B-frags.
// No K-split -> no partial combine; epilogue writes straight from accs.
// ---------------------------------------------------------------------------
__global__ __launch_bounds__(512, 4)
void proj_kernel(const float* __restrict__ x, const unsigned short* __restrict__ swz,
                 unsigned short* __restrict__ q, unsigned short* __restrict__ k,
                 unsigned short* __restrict__ vt)
{
    __shared__ unsigned short xl[32][1032];   // 66 KB; +8 pad vs pow2 stride

    const int tid  = threadIdx.x;
    const int lane = tid & 63, wave = tid >> 6;
    const int quad = lane >> 4, l15 = lane & 15;
    const int mh   = wave >> 2;     // 16-row half
    const int cq   = wave & 3;      // 48-col quarter
    const int m0   = blockIdx.x * 32;

    // ---- phase 1: x slab -> LDS bf16 ----
    {
        const float* xb = x + (size_t)m0 * CDIM;
        float4 t[16];
        #pragma unroll
        for (int i = 0; i < 16; ++i)
            t[i] = *(const float4*)(xb + i * 2048 + tid * 4);   // all independent
        #pragma unroll
        for (int i = 0; i < 16; ++i) {
            const int o = i * 2048 + tid * 4;
            u16x4 p;
            p[0] = f2bf(t[i].x); p[1] = f2bf(t[i].y);
            p[2] = f2bf(t[i].z); p[3] = f2bf(t[i].w);
            *(u16x4*)&xl[o >> 10][o & 1023] = p;
        }
    }
    __syncthreads();

    // ---- phase 2: 32 K-steps, B prefetched 1 ahead ----
    f32x4 acc[3] = {};
    const unsigned short* bp = swz + ((size_t)(cq * 3) * 64 + lane) * 8;
    s16x8 b0 = *(const s16x8*)(bp);
    s16x8 b1 = *(const s16x8*)(bp + 512);
    s16x8 b2 = *(const s16x8*)(bp + 1024);
    bp += 6144;

    #pragma unroll
    for (int ks = 0; ks < 32; ++ks) {
        s16x8 nb0, nb1, nb2;
        if (ks < 31) {
            nb0 = *(const s16x8*)(bp);
            nb1 = *(const s16x8*)(bp + 512);
            nb2 = *(const s16x8*)(bp + 1024);
            bp += 6144;
        }
        const s16x8 af = *(const s16x8*)&xl[mh * 16 + l15][ks * 32 + quad * 8];
        acc[0] = __builtin_amdgcn_mfma_f32_16x16x32_bf16(af, b0, acc[0], 0, 0, 0);
        acc[1] = __builtin_amdgcn_mfma_f32_16x16x32_bf16(af, b1, acc[1], 0, 0, 0);
        acc[2] = __builtin_amdgcn_mfma_f32_16x16x32_bf16(af, b2, acc[2], 0, 0, 0);
        if (ks < 31) { b0 = nb0; b1 = nb1; b2 = nb2; }
    }

    // ---- epilogue: C/D row = quad*4+r, col = cq*48 + t*16 + l15 ----
    const int rowg = m0 + mh * 16 + quad * 4;
    #pragma unroll
    for (int t = 0; t < 3; ++t) {
        const int n = cq * 48 + t * 16 + l15;
        if (n < 64) {
            #pragma unroll
            for (int r = 0; r < 4; ++r)
                q[(size_t)(rowg + r) * HDIM + n] = f2bf(acc[t][r]);
        } else if (n < 128) {
            #pragma unroll
            for (int r = 0; r < 4; ++r)
                k[(size_t)(rowg + r) * HDIM + (n - 64)] = f2bf(acc[t][r]);
        } else {
            const int h  = n - 128;
            const int bb = rowg >> 11, tl = rowg & 2047;
            u16x4 pv;
            #pragma unroll
            for (int r = 0; r < 4; ++r) pv[r] = f2bf(acc[t][r]);
            *(u16x4*)(vt + ((size_t)bb * HDIM + h) * TSEQ + tl) = pv;
        }
    }
}

// ---------------------------------------------------------------------------
// Flash attention pass 1 (split-KV). Block = (q-tile ti, slice s, batch b),
// 256 thr / 4 waves. Slice s owns chunks c ≡ s (mod 4), c < nt = ti/4+1;
// waves round-robin within the slice (each wave <= 2 chunks). Partial
// (O[16][64], l[16]) written to workspace; combined by attn_combine.
// 4096 blocks (4x oversubscribed), big tiles dispatched first.
// ---------------------------------------------------------------------------
__global__ __launch_bounds__(256, 4)
void attn_part(const unsigned short* __restrict__ q, const unsigned short* __restrict__ k,
               const unsigned short* __restrict__ vt, float* __restrict__ Opart,
               float* __restrict__ lpart)
{
    __shared__ unsigned short Pl[4][16][72];   // per-wave P transform
    __shared__ float Olds[4][16][68];          // per-wave O partials
    __shared__ float llds[4][16];

    const int tid  = threadIdx.x;
    const int lane = tid & 63, wave = tid >> 6;
    const int quad = lane >> 4, l15 = lane & 15;
    const int b    = blockIdx.y;
    const int s    = blockIdx.x & 3;
    const int ti   = 127 - ((int)blockIdx.x >> 2);   // biggest tiles first
    const int m0   = ti * 16;
    const int nt   = ti / 4 + 1;

    const unsigned short* qb  = q  + (size_t)b * TSEQ * HDIM;
    const unsigned short* kb  = k  + (size_t)b * TSEQ * HDIM;
    const unsigned short* vtb = vt + (size_t)b * HDIM * TSEQ;

    // Q A-fragments (A[m=l15][k=quad*8+j])
    s16x8 aq[2];
    #pragma unroll
    for (int ks = 0; ks < 2; ++ks)
        aq[ks] = *(const s16x8*)(qb + (size_t)(m0 + l15) * HDIM + ks * 32 + quad * 8);

    f32x4 O[4] = {};
    float l_lane[4] = {0.f, 0.f, 0.f, 0.f};

    // chunks of this slice: c = s + 4*m; wave handles m = wave, wave+4, ...
    for (int c = s + 4 * wave; c < nt; c += 16) {
        const int n0 = c * 64;

        // S = Q K^T
        f32x4 S[4] = {};
        #pragma unroll
        for (int st = 0; st < 4; ++st) {
            const unsigned short* kr = kb + (size_t)(n0 + st * 16 + l15) * HDIM + quad * 8;
            const s16x8 k0 = *(const s16x8*)(kr);
            const s16x8 k1 = *(const s16x8*)(kr + 32);
            S[st] = __builtin_amdgcn_mfma_f32_16x16x32_bf16(aq[0], k0, S[st], 0, 0, 0);
            S[st] = __builtin_amdgcn_mfma_f32_16x16x32_bf16(aq[1], k1, S[st], 0, 0, 0);
        }

        // causal mask + exp2 (no max subtraction; scores bounded ~|3|)
        const int rowbase = m0 + quad * 4;
        #pragma unroll
        for (int st = 0; st < 4; ++st) {
            const int col = n0 + st * 16 + l15;
            #pragma unroll
            for (int r = 0; r < 4; ++r) {
                const float p = (col > rowbase + r) ? 0.f : exp2f(S[st][r]);
                S[st][r] = p;
                l_lane[r] += p;
            }
        }

        // P: C-layout -> A-layout via per-wave LDS slice (same wave, no barrier)
        #pragma unroll
        for (int st = 0; st < 4; ++st)
            #pragma unroll
            for (int r = 0; r < 4; ++r)
                Pl[wave][quad * 4 + r][st * 16 + l15] = f2bf(S[st][r]);
        s16x8 pa[2];
        #pragma unroll
        for (int ks = 0; ks < 2; ++ks)
            pa[ks] = *(const s16x8*)&Pl[wave][l15][ks * 32 + quad * 8];

        // O += P V
        #pragma unroll
        for (int hst = 0; hst < 4; ++hst) {
            const unsigned short* vr = vtb + (size_t)(hst * 16 + l15) * TSEQ + n0 + quad * 8;
            const s16x8 v0 = *(const s16x8*)(vr);
            const s16x8 v1 = *(const s16x8*)(vr + 32);
            O[hst] = __builtin_amdgcn_mfma_f32_16x16x32_bf16(pa[0], v0, O[hst], 0, 0, 0);
            O[hst] = __builtin_amdgcn_mfma_f32_16x16x32_bf16(pa[1], v1, O[hst], 0, 0, 0);
        }
    }

    // l reduction across the 16 lanes of each row group
    #pragma unroll
    for (int off = 1; off < 16; off <<= 1)
        #pragma unroll
        for (int r = 0; r < 4; ++r)
            l_lane[r] += __shfl_xor(l_lane[r], off);

    #pragma unroll
    for (int hst = 0; hst < 4; ++hst)
        #pragma unroll
        for (int r = 0; r < 4; ++r)
            Olds[wave][quad * 4 + r][hst * 16 + l15] = O[hst][r];
    if (l15 == 0) {
        #pragma unroll
        for (int r = 0; r < 4; ++r)
            llds[wave][quad * 4 + r] = l_lane[r];
    }
    __syncthreads();

    // combine 4 waves -> block partial, store to workspace
    const size_t p = ((size_t)b * NTILE + ti) * NSLC + s;
    {
        const int r  = tid >> 4;
        const int c4 = (tid & 15) << 2;
        float4 t;
        float* tp = &t.x;
        #pragma unroll
        for (int j = 0; j < 4; ++j)
            tp[j] = Olds[0][r][c4 + j] + Olds[1][r][c4 + j] +
                    Olds[2][r][c4 + j] + Olds[3][r][c4 + j];
        *(float4*)(Opart + (p * 16 + r) * HDIM + c4) = t;
        if ((tid & 15) == 0)
            lpart[p * 16 + r] = llds[0][r] + llds[1][r] + llds[2][r] + llds[3][r];
    }
}

// ---------------------------------------------------------------------------
// Pass 2: out[row][c4..] = sum_s Opart / sum_s lpart.
// ---------------------------------------------------------------------------
__global__ __launch_bounds__(256)
void attn_combine(const float* __restrict__ Opart, const float* __restrict__ lpart,
                  float* __restrict__ out)
{
    const int g   = blockIdx.x * 256 + threadIdx.x;   // 0 .. 262143
    const int row = g >> 4;                           // 0 .. 16383
    const int c4  = (g & 15) << 2;
    const int b   = row >> 11, t = row & 2047;
    const int ti  = t >> 4,  r = t & 15;
    const size_t p0 = ((size_t)b * NTILE + ti) * NSLC;

    float4 acc = {0.f, 0.f, 0.f, 0.f};
    float lv = 0.f;
    #pragma unroll
    for (int s = 0; s < NSLC; ++s) {
        const float4 t4 = *(const float4*)(Opart + ((p0 + s) * 16 + r) * HDIM + c4);
        acc.x += t4.x; acc.y += t4.y; acc.z += t4.z; acc.w += t4.w;
        lv += lpart[(p0 + s) * 16 + r];
    }
    const float inv = 1.f / lv;
    float4 o = {acc.x * inv, acc.y * inv, acc.z * inv, acc.w * inv};
    *(float4*)(out + (size_t)row * HDIM + c4) = o;
}

// ---------------------------------------------------------------------------
extern "C" void kernel_launch(void* const* d_in, const int* in_sizes, int n_in,
                              void* d_out, int out_size, void* d_ws, size_t ws_size,
                              hipStream_t stream) {
    const float* x  = (const float*)d_in[0];
    const float* Wk = (const float*)d_in[1];
    const float* Wq = (const float*)d_in[2];
    const float* Wv = (const float*)d_in[3];
    float* out = (float*)d_out;

    // ws layout: swz | q | k | vt (bf16) then Opart | lpart (fp32). ~24 MB.
    unsigned short* swz = (unsigned short*)d_ws;            // 196608 elems
    unsigned short* qw  = swz + 196608;
    unsigned short* kw  = qw + (size_t)MROWS * HDIM;
    unsigned short* vtw = kw + (size_t)MROWS * HDIM;
    float* Opart = (float*)(vtw + (size_t)MROWS * HDIM);    // 4096*16*64 fp32
    float* lpart = Opart + (size_t)BATCH * NTILE * NSLC * 16 * HDIM;

    wswz_kernel<<<dim3(768), 256, 0, stream>>>(Wk, Wq, Wv, swz);
    proj_kernel<<<dim3(MROWS / 32), 512, 0, stream>>>(x, swz, qw, kw, vtw);
    attn_part<<<dim3(NTILE * NSLC, BATCH), 256, 0, stream>>>(qw, kw, vtw, Opart, lpart);
    attn_combine<<<dim3(MROWS * 16 / 256), 256, 0, stream>>>(Opart, lpart, out);
}